// Round 10
// baseline (436.172 us; speedup 1.0000x reference)
//
#include <hip/hip_runtime.h>
#include <hip/hip_bf16.h>

#define SLOPE 0.2f
#define EPS_GN 1e-5f
#define APITCH 136  // LDS row pitch in bf16 elems (272 B): 16B-aligned, breaks power-of-2 bank aliasing
#define NBUCK 391   // ceil(100000/256) dst-buckets of 256 nodes
#define BCAP 6144   // staging slots per bucket (mean 4352, huge headroom)

typedef __attribute__((ext_vector_type(8))) short bfrag;   // 8 bf16 = 4 VGPR (MFMA A/B operand)
typedef __attribute__((ext_vector_type(4))) float ffrag;   // 4 fp32 accumulator

__device__ __forceinline__ float lrelu(float v) { return v > 0.f ? v : SLOPE * v; }
__device__ __forceinline__ short f2bs(float v) {
    __hip_bfloat16 h = __float2bfloat16(v);
    return *reinterpret_cast<short*>(&h);
}
__device__ __forceinline__ float blo(unsigned int u) { return __uint_as_float(u << 16); }
__device__ __forceinline__ float bhi(unsigned int u) { return __uint_as_float(u & 0xffff0000u); }

// ============ CSR build: bucketed counting sort, HIST-FREE (R9-proven) ========
// Each bucket owns staging region [b*BCAP, b*BCAP+BCAP): memset(bcur)=0 ->
// scatter (atomic append; weight-prep fused into blocks 0..127) -> finalize
// (computes its own bbase prefix in-block — R10: bucket_scan dispatch folded).
// R3: no grid-resident spin barriers. R7: no block-role fat kernels.
// R8: keep 1-node-per-wave agg granularity on irregular work.

__global__ void __launch_bounds__(256) bucket_scatter(
    const int* __restrict__ ei, int* __restrict__ bcur,
    unsigned int* __restrict__ staging,
    const float* __restrict__ enc_w, const float* __restrict__ enc_b,
    const float* __restrict__ w1, const float* __restrict__ w2,
    unsigned short* __restrict__ WT1b, unsigned short* __restrict__ WT2b,
    float* __restrict__ bc1, float* __restrict__ bc2, int E, int N) {
    __shared__ int h[NBUCK];
    __shared__ int lb[NBUCK];
    __shared__ float w1row[128];
    int t = threadIdx.x, bid = blockIdx.x;
    for (int i = t; i < NBUCK; i += 256) h[i] = 0;
    bool prep = (bid < 128) && (t < 128);
    if (prep) w1row[t] = w1[bid * 128 + t];
    __syncthreads();
    int base = bid * 4096;
    int srcv[16], dstv[16];
#pragma unroll
    for (int s = 0; s < 16; ++s) {
        int e = base + s * 256 + t;
        srcv[s] = -1;
        if (e < E + N) {
            srcv[s] = (e < E) ? ei[e] : (e - E);
            dstv[s] = (e < E) ? ei[E + e] : (e - E);
            atomicAdd(&h[dstv[s] >> 8], 1);
        }
    }
    // fused weight prep: WT1b = bf16(w1@enc_w), bc1 = w1@enc_b, WT2b = bf16(w2)
    if (prep) {
        float acc = 0.f;
        for (int j = 0; j < 128; ++j)
            acc = fmaf(w1row[j], enc_w[j * 128 + t], acc);
        WT1b[bid * 128 + t] = (unsigned short)f2bs(acc);
        WT2b[bid * 128 + t] = (unsigned short)f2bs(w2[bid * 128 + t]);
        if (t == 0) {
            float b = 0.f;
            for (int j = 0; j < 128; ++j) b += w1row[j] * enc_b[j];
            bc1[bid] = b;
            bc2[bid] = 0.f;
        }
    }
    __syncthreads();
    for (int i = t; i < NBUCK; i += 256) {
        int c = h[i];
        lb[i] = c ? atomicAdd(&bcur[i], c) : 0;
        h[i] = 0;  // reuse as within-block cursor
    }
    __syncthreads();
#pragma unroll
    for (int s = 0; s < 16; ++s) {
        if (srcv[s] >= 0) {
            int b = dstv[s] >> 8;
            int slot = atomicAdd(&h[b], 1);
            staging[(size_t)b * BCAP + lb[b] + slot] =
                ((unsigned int)srcv[s] << 8) | (unsigned int)(dstv[s] & 255);
        }
    }
}

// fused: in-block bbase prefix (R10, replaces bucket_scan dispatch) ->
// per-bucket degree hist -> LDS scan -> rowp -> CSR scatter.
__global__ void __launch_bounds__(256) bucket_finalize(
    const unsigned int* __restrict__ staging, const int* __restrict__ bcnt,
    int* __restrict__ rowp, int* __restrict__ esrc, int N, int Etot) {
    int b = blockIdx.x, t = threadIdx.x;
    __shared__ int h[256], sc[256];
    // bbase[b] = sum(bcnt[0..b-1]) — strided partials + tree reduce (L2-hot)
    int ps = 0;
    for (int i = t; i < b; i += 256) ps += bcnt[i];
    sc[t] = ps;
    __syncthreads();
    for (int off = 128; off; off >>= 1) {
        if (t < off) sc[t] += sc[t + off];
        __syncthreads();
    }
    int rbase = sc[0];
    __syncthreads();
    h[t] = 0;
    __syncthreads();
    int cnt = bcnt[b];
    const unsigned int* st = staging + (size_t)b * BCAP;
    for (int j = t; j < cnt; j += 256)
        atomicAdd(&h[st[j] & 255], 1);
    __syncthreads();
    int d = h[t];
    sc[t] = d;
    __syncthreads();
    for (int off = 1; off < 256; off <<= 1) {
        int add = (t >= off) ? sc[t - off] : 0;
        __syncthreads();
        sc[t] += add;
        __syncthreads();
    }
    int excl = rbase + sc[t] - d;
    int node = b * 256 + t;
    if (node < N) rowp[node] = excl;
    if (b == 0 && t == 0) rowp[N] = Etot;
    __syncthreads();
    h[t] = excl;  // within-bucket cursors (global CSR positions)
    __syncthreads();
    for (int j = t; j < cnt; j += 256) {
        unsigned int p = st[j];
        int pos = atomicAdd(&h[p & 255], 1);
        esrc[pos] = (int)(p >> 8);
    }
}

// --------- MFMA GEMM: H[n][128] (bf16) = act(A[n][128]) @ WT^T + bc; + scores --
// R10: MULTI-TILE (T=2). gemm counters (R5): FETCH 20MB, MfmaUtil 1.2% ->
// neither memory- nor MFMA-bound; cost is per-block staging/setup latency.
// Each block now stages Bsh + att/bias registers ONCE and processes 2
// consecutive 64-node tiles (grid 782 ~= the 768 concurrent block slots at
// 3 blocks/CU) — amortizes B-stage 2x and cuts residency rounds 2 -> 1.
// Per-tile arithmetic identical (bitwise). LDS stays 52224 B (R6 boundary).
__global__ void __launch_bounds__(256) gemm_mfma(
    const void* __restrict__ Ain, const unsigned short* __restrict__ WTb,
    const float* __restrict__ bias, const float* __restrict__ att_src,
    const float* __restrict__ att_dst, const int* __restrict__ batch,
    const float* __restrict__ Ac, const float* __restrict__ Bc,
    unsigned int* __restrict__ H, float* __restrict__ ssrc, float* __restrict__ sdst,
    int N, int SB) {
    __shared__ __align__(16) short Bsh[128 * APITCH];  // [c][k] bf16 (34816 B)
    __shared__ __align__(16) short Ash[64 * APITCH];   // [node][k] bf16 (17408 B; reused for C)
    int tid = threadIdx.x;

    int lane = tid & 63, col = lane & 15, quad = lane >> 4;
    int w = tid >> 6;
    int rowBase = w * 16;

    // per-lane register loads (loop-invariant; replaces LDS score/bias arrays)
    float2 av = *(const float2*)&att_src[lane * 2];
    float2 dv = *(const float2*)&att_dst[lane * 2];
    float bvr[8];
#pragma unroll
    for (int t = 0; t < 8; ++t) bvr[t] = bias[t * 16 + col];

    for (int idx = tid; idx < 2048; idx += 256) {
        int c = idx >> 4, k8 = (idx & 15) * 8;
        uint4 wv = ((const uint4*)WTb)[idx];
        *(uint4*)&Bsh[c * APITCH + k8] = wv;
    }

    int t0 = blockIdx.x * 2;
    int t1 = min(t0 + 2, SB);
    for (int tile = t0; tile < t1; ++tile) {
        int base = tile * 64;
        __syncthreads();  // prev epilogue's Ash reads done (covers B-stage on iter 0)

        if (Ac == nullptr) {
            const float* A = (const float*)Ain;
            for (int idx = tid; idx < 2048; idx += 256) {
                int nl = idx >> 5, k4 = (idx & 31) * 4;
                int node = base + nl;
                float4 v = make_float4(0.f, 0.f, 0.f, 0.f);
                if (node < N) v = ((const float4*)A)[node * 32 + (idx & 31)];
                *(short4*)&Ash[nl * APITCH + k4] =
                    make_short4(f2bs(v.x), f2bs(v.y), f2bs(v.z), f2bs(v.w));
            }
        } else {
            const uint4* A4 = (const uint4*)Ain;
            for (int idx = tid; idx < 1024; idx += 256) {
                int nl = idx >> 4, u4 = idx & 15, k8 = u4 * 8;
                int node = base + nl;
                short o[8] = {0, 0, 0, 0, 0, 0, 0, 0};
                if (node < N) {
                    uint4 hb = A4[node * 16 + u4];
                    int g = batch[node];
                    float4 a0 = *(const float4*)&Ac[g * 128 + k8];
                    float4 a1 = *(const float4*)&Ac[g * 128 + k8 + 4];
                    float4 b0 = *(const float4*)&Bc[g * 128 + k8];
                    float4 b1 = *(const float4*)&Bc[g * 128 + k8 + 4];
                    o[0] = f2bs(fmaf(blo(hb.x), a0.x, b0.x));
                    o[1] = f2bs(fmaf(bhi(hb.x), a0.y, b0.y));
                    o[2] = f2bs(fmaf(blo(hb.y), a0.z, b0.z));
                    o[3] = f2bs(fmaf(bhi(hb.y), a0.w, b0.w));
                    o[4] = f2bs(fmaf(blo(hb.z), a1.x, b1.x));
                    o[5] = f2bs(fmaf(bhi(hb.z), a1.y, b1.y));
                    o[6] = f2bs(fmaf(blo(hb.w), a1.z, b1.z));
                    o[7] = f2bs(fmaf(bhi(hb.w), a1.w, b1.w));
                }
                *(bfrag*)&Ash[nl * APITCH + k8] = *(bfrag*)o;
            }
        }
        __syncthreads();

        bfrag afr[4];
#pragma unroll
        for (int s = 0; s < 4; ++s)
            afr[s] = *(const bfrag*)&Ash[(rowBase + col) * APITCH + s * 32 + quad * 8];

        ffrag acc[8];
#pragma unroll
        for (int t = 0; t < 8; ++t) acc[t] = (ffrag){0.f, 0.f, 0.f, 0.f};

#pragma unroll
        for (int t = 0; t < 8; ++t) {
#pragma unroll
            for (int s = 0; s < 4; ++s) {
                bfrag bfr = *(const bfrag*)&Bsh[(t * 16 + col) * APITCH + s * 32 + quad * 8];
                acc[t] = __builtin_amdgcn_mfma_f32_16x16x32_bf16(afr[s], bfr, acc[t], 0, 0, 0);
            }
        }

#pragma unroll
        for (int t = 0; t < 8; ++t) {
            int ch = t * 16 + col;
            float bv = bvr[t];
#pragma unroll
            for (int r = 0; r < 4; ++r)
                Ash[(rowBase + quad * 4 + r) * APITCH + ch] = f2bs(acc[t][r] + bv);
        }
        __syncthreads();

        for (int r = 0; r < 16; ++r) {
            int node = base + rowBase + r;
            unsigned int hb = *(const unsigned int*)&Ash[(rowBase + r) * APITCH + lane * 2];
            float hx = blo(hb);
            float hy = bhi(hb);
            float vs = hx * av.x + hy * av.y;
            float vd = hx * dv.x + hy * dv.y;
#pragma unroll
            for (int off = 8; off; off >>= 1) {
                vs += __shfl_xor(vs, off, 16);
                vd += __shfl_xor(vd, off, 16);
            }
            if (node < N) {
                H[node * 64 + lane] = hb;
                if ((lane & 15) == 0) {
                    int h = lane >> 4;
                    ssrc[node * 4 + h] = vs;
                    sdst[node * 4 + h] = vd;
                }
            }
        }
    }
}

// ------- aggregation: single-pass softmax num+den; ONE WAVE PER NODE ----------
// R2/R6 form: 100k independent single-node waves preserve scheduler load
// balancing on the irregular degree dist. FETCH at the compulsory per-XCD
// floor (~239MB) -> throughput-bound; inner loop untouched.
__global__ void __launch_bounds__(256) agg_kernel(
    const int* __restrict__ row, const int* __restrict__ esrc,
    const float* __restrict__ ssrc, const float* __restrict__ sdst,
    const uint4* __restrict__ H4, const float* __restrict__ bias,
    uint4* __restrict__ out, int N) {
    int n = (blockIdx.x * 256 + threadIdx.x) >> 6;
    int lane = threadIdx.x & 63;
    if (n >= N) return;
    int slot = lane >> 4, li = lane & 15, head = li >> 2;
    int beg = row[n], end = row[n + 1];
    int last = end - 1;
    float sdh = sdst[n * 4 + head];

    float num[8] = {0.f, 0.f, 0.f, 0.f, 0.f, 0.f, 0.f, 0.f};
    float den = 0.f;
    for (int ebase = beg; ebase < end; ebase += 20) {
        int sv[5];
        float av[5];
        uint4 hv[5];
        bool ok[5];
#pragma unroll
        for (int j = 0; j < 5; ++j) {
            int e = ebase + slot + 4 * j;
            ok[j] = (e < end);
            sv[j] = esrc[min(e, last)];
        }
#pragma unroll
        for (int j = 0; j < 5; ++j) {
            av[j] = ssrc[sv[j] * 4 + head];
            hv[j] = H4[sv[j] * 16 + li];
        }
        __builtin_amdgcn_sched_barrier(0);
#pragma unroll
        for (int j = 0; j < 5; ++j) {
            float al = ok[j] ? __expf(lrelu(av[j] + sdh)) : 0.f;
            den += al;
            num[0] = fmaf(al, blo(hv[j].x), num[0]);
            num[1] = fmaf(al, bhi(hv[j].x), num[1]);
            num[2] = fmaf(al, blo(hv[j].y), num[2]);
            num[3] = fmaf(al, bhi(hv[j].y), num[3]);
            num[4] = fmaf(al, blo(hv[j].z), num[4]);
            num[5] = fmaf(al, bhi(hv[j].z), num[5]);
            num[6] = fmaf(al, blo(hv[j].w), num[6]);
            num[7] = fmaf(al, bhi(hv[j].w), num[7]);
        }
    }
    den += __shfl_xor(den, 16);
    den += __shfl_xor(den, 32);
#pragma unroll
    for (int j = 0; j < 8; ++j) {
        num[j] += __shfl_xor(num[j], 16);
        num[j] += __shfl_xor(num[j], 32);
    }
    if (slot == 0) {
        float rh = 1.f / den;
        int c0 = li * 8;
        unsigned int o[4];
#pragma unroll
        for (int p = 0; p < 4; ++p) {
            float v0 = fmaf(num[2 * p], rh, bias[c0 + 2 * p]);
            float v1 = fmaf(num[2 * p + 1], rh, bias[c0 + 2 * p + 1]);
            v0 = v0 > 0.f ? v0 : __expf(v0) - 1.f;  // ELU
            v1 = v1 > 0.f ? v1 : __expf(v1) - 1.f;
            o[p] = ((unsigned int)(unsigned short)f2bs(v0)) |
                   (((unsigned int)(unsigned short)f2bs(v1)) << 16);
        }
        out[n * 16 + li] = make_uint4(o[0], o[1], o[2], o[3]);
    }
}

// ------- GraphNorm stats (+ max/min for layer 2) — ATOMIC-FREE ----------------
template <int POOL>
__global__ void __launch_bounds__(256) stats_kernel(
    const uint4* __restrict__ X4, const int* __restrict__ batch,
    float* __restrict__ part, int N) {
    __shared__ float red[16][16][9];  // [rowgroup][u4][ch(+pad)]
    int t = threadIdx.x, u4 = t & 15, rg = t >> 4;
    int base = blockIdx.x * 64;
    int g0 = batch[base];

    float s[2][8] = {}, q[2][8] = {};
    float mx[2][8], mn[2][8];
#pragma unroll
    for (int st = 0; st < 2; ++st)
#pragma unroll
        for (int p = 0; p < 8; ++p) { mx[st][p] = -3e38f; mn[st][p] = 3e38f; }

#pragma unroll
    for (int rr = 0; rr < 4; ++rr) {
        int node = base + rg + rr * 16;
        if (node < N) {
            uint4 hb = X4[node * 16 + u4];
            int st = (batch[node] != g0) ? 1 : 0;
            float vv[8] = {blo(hb.x), bhi(hb.x), blo(hb.y), bhi(hb.y),
                           blo(hb.z), bhi(hb.z), blo(hb.w), bhi(hb.w)};
#pragma unroll
            for (int p = 0; p < 8; ++p) {
                s[st][p] += vv[p];
                q[st][p] += vv[p] * vv[p];
                if (POOL) {
                    mx[st][p] = fmaxf(mx[st][p], vv[p]);
                    mn[st][p] = fminf(mn[st][p], vv[p]);
                }
            }
        }
    }

    int uu = t >> 3, ch = t & 7;  // reducer mapping (threads 0..127 -> channel t)
    float rs[2] = {0.f, 0.f}, rq[2] = {0.f, 0.f};
    float rmx[2] = {-3e38f, -3e38f}, rmn[2] = {3e38f, 3e38f};
    for (int st = 0; st < 2; ++st) {
#pragma unroll
        for (int p = 0; p < 8; ++p) red[rg][u4][p] = s[st][p];
        __syncthreads();
        if (t < 128) { float a = 0.f; for (int r2 = 0; r2 < 16; ++r2) a += red[r2][uu][ch]; rs[st] = a; }
        __syncthreads();
#pragma unroll
        for (int p = 0; p < 8; ++p) red[rg][u4][p] = q[st][p];
        __syncthreads();
        if (t < 128) { float a = 0.f; for (int r2 = 0; r2 < 16; ++r2) a += red[r2][uu][ch]; rq[st] = a; }
        __syncthreads();
        if (POOL) {
#pragma unroll
            for (int p = 0; p < 8; ++p) red[rg][u4][p] = mx[st][p];
            __syncthreads();
            if (t < 128) { float a = -3e38f; for (int r2 = 0; r2 < 16; ++r2) a = fmaxf(a, red[r2][uu][ch]); rmx[st] = a; }
            __syncthreads();
#pragma unroll
            for (int p = 0; p < 8; ++p) red[rg][u4][p] = mn[st][p];
            __syncthreads();
            if (t < 128) { float a = 3e38f; for (int r2 = 0; r2 < 16; ++r2) a = fminf(a, red[r2][uu][ch]); rmn[st] = a; }
            __syncthreads();
        }
    }
    if (t < 128) {
        float* pb = part + (size_t)blockIdx.x * 8 * 128;
        pb[0 * 128 + t] = rs[0];
        pb[1 * 128 + t] = rq[0];
        pb[2 * 128 + t] = rs[1];
        pb[3 * 128 + t] = rq[1];
        if (POOL) {
            pb[4 * 128 + t] = rmx[0];
            pb[5 * 128 + t] = rmn[0];
            pb[6 * 128 + t] = rmx[1];
            pb[7 * 128 + t] = rmn[1];
        }
    }
}

// per-group gather of block partials -> GraphNorm coefficients Ac/Bc.
__global__ void reduce_coef0(const float* __restrict__ part,
                             const int* __restrict__ batch, int N,
                             const float* __restrict__ w, const float* __restrict__ b,
                             const float* __restrict__ ms,
                             float* __restrict__ Ac, float* __restrict__ Bc) {
    __shared__ int sh2[2];
    int g = blockIdx.x, c = threadIdx.x;  // 64 x 128
    if (c < 2) {
        int key = g + c;  // lower_bound(batch, key)
        int lo = 0, hi = N;
        while (lo < hi) { int m = (lo + hi) >> 1; if (batch[m] < key) lo = m + 1; else hi = m; }
        sh2[c] = lo;
    }
    __syncthreads();
    int sidx = sh2[0], eidx = sh2[1];
    float cnt = (float)(eidx - sidx);
    if (cnt < 0.5f) {
        Ac[g * 128 + c] = 0.f;
        Bc[g * 128 + c] = 0.f;
        return;
    }
    int b0 = sidx >> 6, b1 = (eidx - 1) >> 6;
    float s = 0.f, q = 0.f;
    for (int bb = b0; bb <= b1; ++bb) {
        int g0b = batch[bb << 6];
        int qoff;
        bool take;
        if (g0b == g) { qoff = 0; take = true; }
        else {
            int g1b = batch[min((bb << 6) + 63, N - 1)];
            take = (g1b == g);
            qoff = 2;
        }
        if (take) {
            const float* pb = part + (size_t)bb * 8 * 128;
            s += pb[qoff * 128 + c];
            q += pb[(qoff + 1) * 128 + c];
        }
    }
    float mean = s / cnt;
    float msv = ms[c];
    float var = q / cnt - msv * (2.f - msv) * mean * mean;
    var = fmaxf(var, 0.f);
    float inv = rsqrtf(var + EPS_GN);
    float a = w[c] * inv;
    float bb2 = b[c] - msv * mean * a;
    Ac[g * 128 + c] = a;
    Bc[g * 128 + c] = bb2;
}

// per-group partial gather -> GraphNorm coef -> monotone-affine pooled -> FC.
__global__ void rc_fc(const float* __restrict__ part,
                      const int* __restrict__ batch, int N,
                      const float* __restrict__ w, const float* __restrict__ b,
                      const float* __restrict__ ms,
                      const float* __restrict__ fcw,
                      const float* __restrict__ fcb,
                      float* __restrict__ out) {
    __shared__ int sh2[2];
    __shared__ float prow[128];
    int g = blockIdx.x, c = threadIdx.x;  // 64 x 128
    if (c < 2) {
        int key = g + c;  // lower_bound(batch, key)
        int lo = 0, hi = N;
        while (lo < hi) { int m = (lo + hi) >> 1; if (batch[m] < key) lo = m + 1; else hi = m; }
        sh2[c] = lo;
    }
    __syncthreads();
    int sidx = sh2[0], eidx = sh2[1];
    float cnt = (float)(eidx - sidx);
    float pooledv = 0.f;
    if (cnt >= 0.5f) {
        int b0 = sidx >> 6, b1 = (eidx - 1) >> 6;
        float s = 0.f, q = 0.f, M = -3e38f, m = 3e38f;
        for (int bb = b0; bb <= b1; ++bb) {
            int g0b = batch[bb << 6];
            int qoff;
            bool take;
            if (g0b == g) { qoff = 0; take = true; }
            else {
                int g1b = batch[min((bb << 6) + 63, N - 1)];
                take = (g1b == g);
                qoff = 2;
            }
            if (take) {
                const float* pb = part + (size_t)bb * 8 * 128;
                s += pb[qoff * 128 + c];
                q += pb[(qoff + 1) * 128 + c];
                M = fmaxf(M, pb[(4 + qoff) * 128 + c]);
                m = fminf(m, pb[(5 + qoff) * 128 + c]);
            }
        }
        float mean = s / cnt;
        float msv = ms[c];
        float var = q / cnt - msv * (2.f - msv) * mean * mean;
        var = fmaxf(var, 0.f);
        float inv = rsqrtf(var + EPS_GN);
        float a = w[c] * inv;
        float bb2 = b[c] - msv * mean * a;
        pooledv = (a >= 0.f) ? fmaf(a, M, bb2) : fmaf(a, m, bb2);
    }
    prow[c] = pooledv;
    __syncthreads();
    if (c < 64) {
        float acc = fcb[c];
        for (int k = 0; k < 128; ++k)
            acc = fmaf(prow[k], fcw[c * 128 + k], acc);
        out[g * 64 + c] = acc;
    }
}

extern "C" void kernel_launch(void* const* d_in, const int* in_sizes, int n_in,
                              void* d_out, int out_size, void* d_ws, size_t ws_size,
                              hipStream_t stream) {
    const float* x     = (const float*)d_in[0];
    const int* ei      = (const int*)d_in[1];
    const int* batch   = (const int*)d_in[2];
    const float* enc_w = (const float*)d_in[3];
    const float* enc_b = (const float*)d_in[4];
    const float* w1    = (const float*)d_in[5];
    const float* as1   = (const float*)d_in[6];
    const float* ad1   = (const float*)d_in[7];
    const float* b1    = (const float*)d_in[8];
    const float* n1w   = (const float*)d_in[9];
    const float* n1b   = (const float*)d_in[10];
    const float* n1ms  = (const float*)d_in[11];
    const float* w2    = (const float*)d_in[12];
    const float* as2   = (const float*)d_in[13];
    const float* ad2   = (const float*)d_in[14];
    const float* b2    = (const float*)d_in[15];
    const float* n2w   = (const float*)d_in[16];
    const float* n2b   = (const float*)d_in[17];
    const float* n2ms  = (const float*)d_in[18];
    const float* fcw   = (const float*)d_in[19];
    const float* fcb   = (const float*)d_in[20];
    float* out = (float*)d_out;

    int N = in_sizes[2];
    int E = in_sizes[1] / 2;
    int Etot = E + N;
    int SB = (N + 63) / 64;
    int GB = (SB + 1) / 2;  // multi-tile gemm grid (T=2)

    char* ws = (char*)d_ws;
    size_t off = 0;
    auto take = [&](size_t bytes) {
        char* p = ws + off;
        off = (off + bytes + 255) & ~(size_t)255;
        return p;
    };
    unsigned short* WT1b = (unsigned short*)take(128 * 128 * 2);
    unsigned short* WT2b = (unsigned short*)take(128 * 128 * 2);
    float* bc1 = (float*)take(512);
    float* bc2 = (float*)take(512);
    float* ssrc = (float*)take((size_t)N * 16);
    float* sdst = (float*)take((size_t)N * 16);
    int* rowp   = (int*)take((size_t)(N + 1) * 4);
    int* esrc   = (int*)take((size_t)Etot * 4);
    unsigned int* staging = (unsigned int*)take((size_t)NBUCK * BCAP * 4);
    int* bcur   = (int*)take(512 * 4);
    unsigned int* H = (unsigned int*)take((size_t)N * 256);  // bf16 [N][128]
    unsigned int* AG = (unsigned int*)take((size_t)N * 256); // bf16 [N][128]
    float* Ac   = (float*)take(64 * 128 * 4);
    float* Bc   = (float*)take(64 * 128 * 4);
    float* part = (float*)take((size_t)SB * 8 * 128 * 4);    // per-block partials
    if (off > ws_size) return;  // workspace too small -> output stays zero

    int EB = (Etot + 4095) / 4096;

    hipMemsetAsync(bcur, 0, 512 * 4, stream);

    // ---- CSR build, hist-free (weight prep fused into scatter; scan folded
    //      into finalize) ----
    bucket_scatter<<<EB, 256, 0, stream>>>(ei, bcur, staging, enc_w, enc_b,
                                           w1, w2, WT1b, WT2b, bc1, bc2, E, N);
    bucket_finalize<<<NBUCK, 256, 0, stream>>>(staging, bcur, rowp, esrc, N, Etot);

    // ---- layer 1 (encoder folded into WT1b/bc1) ----
    gemm_mfma<<<GB, 256, 0, stream>>>(x, WT1b, bc1, as1, ad1, batch,
                                      nullptr, nullptr, H, ssrc, sdst, N, SB);
    agg_kernel<<<(N + 3) / 4, 256, 0, stream>>>(rowp, esrc, ssrc, sdst,
                                                (const uint4*)H, b1, (uint4*)AG, N);
    stats_kernel<0><<<SB, 256, 0, stream>>>((const uint4*)AG, batch, part, N);
    reduce_coef0<<<64, 128, 0, stream>>>(part, batch, N, n1w, n1b, n1ms, Ac, Bc);

    // ---- layer 2 (GraphNorm fused into gemm A-staging; stats+pool one pass) ----
    gemm_mfma<<<GB, 256, 0, stream>>>(AG, WT2b, bc2, as2, ad2, batch,
                                      Ac, Bc, H, ssrc, sdst, N, SB);
    agg_kernel<<<(N + 3) / 4, 256, 0, stream>>>(rowp, esrc, ssrc, sdst,
                                                (const uint4*)H, b2, (uint4*)AG, N);
    stats_kernel<1><<<SB, 256, 0, stream>>>((const uint4*)AG, batch, part, N);
    rc_fc<<<64, 128, 0, stream>>>(part, batch, N, n2w, n2b, n2ms, fcw, fcb, out);
}

// Round 11
// 427.615 us; speedup vs baseline: 1.0200x; 1.0200x over previous
//
#include <hip/hip_runtime.h>
#include <hip/hip_bf16.h>

#define SLOPE 0.2f
#define EPS_GN 1e-5f
#define APITCH 136  // LDS row pitch in bf16 elems (272 B): 16B-aligned, breaks power-of-2 bank aliasing
#define NBUCK 391   // ceil(100000/256) dst-buckets of 256 nodes
#define BCAP 6144   // staging slots per bucket (mean 4352, huge headroom)

typedef __attribute__((ext_vector_type(8))) short bfrag;   // 8 bf16 = 4 VGPR (MFMA A/B operand)
typedef __attribute__((ext_vector_type(4))) float ffrag;   // 4 fp32 accumulator

__device__ __forceinline__ float lrelu(float v) { return v > 0.f ? v : SLOPE * v; }
__device__ __forceinline__ short f2bs(float v) {
    __hip_bfloat16 h = __float2bfloat16(v);
    return *reinterpret_cast<short*>(&h);
}
__device__ __forceinline__ float blo(unsigned int u) { return __uint_as_float(u << 16); }
__device__ __forceinline__ float bhi(unsigned int u) { return __uint_as_float(u & 0xffff0000u); }

// ============ CSR build: bucketed counting sort, HIST-FREE (R9-proven) ========
// Each bucket owns staging region [b*BCAP, b*BCAP+BCAP): memset(bcur)=0 ->
// scatter (atomic append; weight-prep fused into blocks 0..127) -> finalize
// (computes its own bbase prefix in-block — R11 keeps this fold; bucket_scan
// dispatch removed). R3: no grid-resident spin barriers. R7: no block-role
// fat kernels. R8/R10: never coarsen block granularity (irregular OR regular
// work) — scheduler interleave beats staging amortization on this chip.

__global__ void __launch_bounds__(256) bucket_scatter(
    const int* __restrict__ ei, int* __restrict__ bcur,
    unsigned int* __restrict__ staging,
    const float* __restrict__ enc_w, const float* __restrict__ enc_b,
    const float* __restrict__ w1, const float* __restrict__ w2,
    unsigned short* __restrict__ WT1b, unsigned short* __restrict__ WT2b,
    float* __restrict__ bc1, float* __restrict__ bc2, int E, int N) {
    __shared__ int h[NBUCK];
    __shared__ int lb[NBUCK];
    __shared__ float w1row[128];
    int t = threadIdx.x, bid = blockIdx.x;
    for (int i = t; i < NBUCK; i += 256) h[i] = 0;
    bool prep = (bid < 128) && (t < 128);
    if (prep) w1row[t] = w1[bid * 128 + t];
    __syncthreads();
    int base = bid * 4096;
    int srcv[16], dstv[16];
#pragma unroll
    for (int s = 0; s < 16; ++s) {
        int e = base + s * 256 + t;
        srcv[s] = -1;
        if (e < E + N) {
            srcv[s] = (e < E) ? ei[e] : (e - E);
            dstv[s] = (e < E) ? ei[E + e] : (e - E);
            atomicAdd(&h[dstv[s] >> 8], 1);
        }
    }
    // fused weight prep: WT1b = bf16(w1@enc_w), bc1 = w1@enc_b, WT2b = bf16(w2)
    if (prep) {
        float acc = 0.f;
        for (int j = 0; j < 128; ++j)
            acc = fmaf(w1row[j], enc_w[j * 128 + t], acc);
        WT1b[bid * 128 + t] = (unsigned short)f2bs(acc);
        WT2b[bid * 128 + t] = (unsigned short)f2bs(w2[bid * 128 + t]);
        if (t == 0) {
            float b = 0.f;
            for (int j = 0; j < 128; ++j) b += w1row[j] * enc_b[j];
            bc1[bid] = b;
            bc2[bid] = 0.f;
        }
    }
    __syncthreads();
    for (int i = t; i < NBUCK; i += 256) {
        int c = h[i];
        lb[i] = c ? atomicAdd(&bcur[i], c) : 0;
        h[i] = 0;  // reuse as within-block cursor
    }
    __syncthreads();
#pragma unroll
    for (int s = 0; s < 16; ++s) {
        if (srcv[s] >= 0) {
            int b = dstv[s] >> 8;
            int slot = atomicAdd(&h[b], 1);
            staging[(size_t)b * BCAP + lb[b] + slot] =
                ((unsigned int)srcv[s] << 8) | (unsigned int)(dstv[s] & 255);
        }
    }
}

// fused: in-block bbase prefix (replaces bucket_scan dispatch) ->
// per-bucket degree hist -> LDS scan -> rowp -> CSR scatter.
__global__ void __launch_bounds__(256) bucket_finalize(
    const unsigned int* __restrict__ staging, const int* __restrict__ bcnt,
    int* __restrict__ rowp, int* __restrict__ esrc, int N, int Etot) {
    int b = blockIdx.x, t = threadIdx.x;
    __shared__ int h[256], sc[256];
    // bbase[b] = sum(bcnt[0..b-1]) — strided partials + tree reduce (L2-hot)
    int ps = 0;
    for (int i = t; i < b; i += 256) ps += bcnt[i];
    sc[t] = ps;
    __syncthreads();
    for (int off = 128; off; off >>= 1) {
        if (t < off) sc[t] += sc[t + off];
        __syncthreads();
    }
    int rbase = sc[0];
    __syncthreads();
    h[t] = 0;
    __syncthreads();
    int cnt = bcnt[b];
    const unsigned int* st = staging + (size_t)b * BCAP;
    for (int j = t; j < cnt; j += 256)
        atomicAdd(&h[st[j] & 255], 1);
    __syncthreads();
    int d = h[t];
    sc[t] = d;
    __syncthreads();
    for (int off = 1; off < 256; off <<= 1) {
        int add = (t >= off) ? sc[t - off] : 0;
        __syncthreads();
        sc[t] += add;
        __syncthreads();
    }
    int excl = rbase + sc[t] - d;
    int node = b * 256 + t;
    if (node < N) rowp[node] = excl;
    if (b == 0 && t == 0) rowp[N] = Etot;
    __syncthreads();
    h[t] = excl;  // within-bucket cursors (global CSR positions)
    __syncthreads();
    for (int j = t; j < cnt; j += 256) {
        unsigned int p = st[j];
        int pos = atomicAdd(&h[p & 255], 1);
        esrc[pos] = (int)(p >> 8);
    }
}

// --------- MFMA GEMM: H[n][128] (bf16) = act(A[n][128]) @ WT^T + bc; + scores --
// R9 single-tile form restored (R10's T=2 multi-tile regressed +8us: grid 782
// vs 768 block slots -> 14-block straggler round running 2 serial tiles each;
// scheduler interleave of 1563 fine blocks beats the 32KB B-stage
// amortization). LDS 52224 B -> 3 blocks/CU (R4-R6 empirical boundary);
// att/bias in registers; layer-1 fp32 A (Ac==nullptr), layer-2 applies
// global Ac/Bc GraphNorm coefficients during A-staging.
__global__ void __launch_bounds__(256) gemm_mfma(
    const void* __restrict__ Ain, const unsigned short* __restrict__ WTb,
    const float* __restrict__ bias, const float* __restrict__ att_src,
    const float* __restrict__ att_dst, const int* __restrict__ batch,
    const float* __restrict__ Ac, const float* __restrict__ Bc,
    unsigned int* __restrict__ H, float* __restrict__ ssrc, float* __restrict__ sdst, int N) {
    __shared__ __align__(16) short Bsh[128 * APITCH];  // [c][k] bf16 (34816 B)
    __shared__ __align__(16) short Ash[64 * APITCH];   // [node][k] bf16 (17408 B; reused for C)
    int tid = threadIdx.x;
    int base = blockIdx.x * 64;

    int lane = tid & 63, col = lane & 15, quad = lane >> 4;
    int w = tid >> 6;
    int rowBase = w * 16;

    // per-lane register loads (replaces LDS score/bias arrays; L2-hot)
    float2 av = *(const float2*)&att_src[lane * 2];
    float2 dv = *(const float2*)&att_dst[lane * 2];
    float bvr[8];
#pragma unroll
    for (int t = 0; t < 8; ++t) bvr[t] = bias[t * 16 + col];

    for (int idx = tid; idx < 2048; idx += 256) {
        int c = idx >> 4, k8 = (idx & 15) * 8;
        uint4 wv = ((const uint4*)WTb)[idx];
        *(uint4*)&Bsh[c * APITCH + k8] = wv;
    }
    if (Ac == nullptr) {
        const float* A = (const float*)Ain;
        for (int idx = tid; idx < 2048; idx += 256) {
            int nl = idx >> 5, k4 = (idx & 31) * 4;
            int node = base + nl;
            float4 v = make_float4(0.f, 0.f, 0.f, 0.f);
            if (node < N) v = ((const float4*)A)[node * 32 + (idx & 31)];
            *(short4*)&Ash[nl * APITCH + k4] =
                make_short4(f2bs(v.x), f2bs(v.y), f2bs(v.z), f2bs(v.w));
        }
    } else {
        const uint4* A4 = (const uint4*)Ain;
        for (int idx = tid; idx < 1024; idx += 256) {
            int nl = idx >> 4, u4 = idx & 15, k8 = u4 * 8;
            int node = base + nl;
            short o[8] = {0, 0, 0, 0, 0, 0, 0, 0};
            if (node < N) {
                uint4 hb = A4[node * 16 + u4];
                int g = batch[node];
                float4 a0 = *(const float4*)&Ac[g * 128 + k8];
                float4 a1 = *(const float4*)&Ac[g * 128 + k8 + 4];
                float4 b0 = *(const float4*)&Bc[g * 128 + k8];
                float4 b1 = *(const float4*)&Bc[g * 128 + k8 + 4];
                o[0] = f2bs(fmaf(blo(hb.x), a0.x, b0.x));
                o[1] = f2bs(fmaf(bhi(hb.x), a0.y, b0.y));
                o[2] = f2bs(fmaf(blo(hb.y), a0.z, b0.z));
                o[3] = f2bs(fmaf(bhi(hb.y), a0.w, b0.w));
                o[4] = f2bs(fmaf(blo(hb.z), a1.x, b1.x));
                o[5] = f2bs(fmaf(bhi(hb.z), a1.y, b1.y));
                o[6] = f2bs(fmaf(blo(hb.w), a1.z, b1.z));
                o[7] = f2bs(fmaf(bhi(hb.w), a1.w, b1.w));
            }
            *(bfrag*)&Ash[nl * APITCH + k8] = *(bfrag*)o;
        }
    }
    __syncthreads();

    bfrag afr[4];
#pragma unroll
    for (int s = 0; s < 4; ++s)
        afr[s] = *(const bfrag*)&Ash[(rowBase + col) * APITCH + s * 32 + quad * 8];

    ffrag acc[8];
#pragma unroll
    for (int t = 0; t < 8; ++t) acc[t] = (ffrag){0.f, 0.f, 0.f, 0.f};

#pragma unroll
    for (int t = 0; t < 8; ++t) {
#pragma unroll
        for (int s = 0; s < 4; ++s) {
            bfrag bfr = *(const bfrag*)&Bsh[(t * 16 + col) * APITCH + s * 32 + quad * 8];
            acc[t] = __builtin_amdgcn_mfma_f32_16x16x32_bf16(afr[s], bfr, acc[t], 0, 0, 0);
        }
    }

#pragma unroll
    for (int t = 0; t < 8; ++t) {
        int ch = t * 16 + col;
        float bv = bvr[t];
#pragma unroll
        for (int r = 0; r < 4; ++r)
            Ash[(rowBase + quad * 4 + r) * APITCH + ch] = f2bs(acc[t][r] + bv);
    }
    __syncthreads();

    for (int r = 0; r < 16; ++r) {
        int node = base + rowBase + r;
        unsigned int hb = *(const unsigned int*)&Ash[(rowBase + r) * APITCH + lane * 2];
        float hx = blo(hb);
        float hy = bhi(hb);
        float vs = hx * av.x + hy * av.y;
        float vd = hx * dv.x + hy * dv.y;
#pragma unroll
        for (int off = 8; off; off >>= 1) {
            vs += __shfl_xor(vs, off, 16);
            vd += __shfl_xor(vd, off, 16);
        }
        if (node < N) {
            H[node * 64 + lane] = hb;
            if ((lane & 15) == 0) {
                int h = lane >> 4;
                ssrc[node * 4 + h] = vs;
                sdst[node * 4 + h] = vd;
            }
        }
    }
}

// ------- aggregation: single-pass softmax num+den; ONE WAVE PER NODE ----------
// R2/R6 form: 100k independent single-node waves preserve scheduler load
// balancing on the irregular degree dist. FETCH at the compulsory per-XCD
// floor (~239MB) -> throughput-bound; inner loop untouched.
__global__ void __launch_bounds__(256) agg_kernel(
    const int* __restrict__ row, const int* __restrict__ esrc,
    const float* __restrict__ ssrc, const float* __restrict__ sdst,
    const uint4* __restrict__ H4, const float* __restrict__ bias,
    uint4* __restrict__ out, int N) {
    int n = (blockIdx.x * 256 + threadIdx.x) >> 6;
    int lane = threadIdx.x & 63;
    if (n >= N) return;
    int slot = lane >> 4, li = lane & 15, head = li >> 2;
    int beg = row[n], end = row[n + 1];
    int last = end - 1;
    float sdh = sdst[n * 4 + head];

    float num[8] = {0.f, 0.f, 0.f, 0.f, 0.f, 0.f, 0.f, 0.f};
    float den = 0.f;
    for (int ebase = beg; ebase < end; ebase += 20) {
        int sv[5];
        float av[5];
        uint4 hv[5];
        bool ok[5];
#pragma unroll
        for (int j = 0; j < 5; ++j) {
            int e = ebase + slot + 4 * j;
            ok[j] = (e < end);
            sv[j] = esrc[min(e, last)];
        }
#pragma unroll
        for (int j = 0; j < 5; ++j) {
            av[j] = ssrc[sv[j] * 4 + head];
            hv[j] = H4[sv[j] * 16 + li];
        }
        __builtin_amdgcn_sched_barrier(0);
#pragma unroll
        for (int j = 0; j < 5; ++j) {
            float al = ok[j] ? __expf(lrelu(av[j] + sdh)) : 0.f;
            den += al;
            num[0] = fmaf(al, blo(hv[j].x), num[0]);
            num[1] = fmaf(al, bhi(hv[j].x), num[1]);
            num[2] = fmaf(al, blo(hv[j].y), num[2]);
            num[3] = fmaf(al, bhi(hv[j].y), num[3]);
            num[4] = fmaf(al, blo(hv[j].z), num[4]);
            num[5] = fmaf(al, bhi(hv[j].z), num[5]);
            num[6] = fmaf(al, blo(hv[j].w), num[6]);
            num[7] = fmaf(al, bhi(hv[j].w), num[7]);
        }
    }
    den += __shfl_xor(den, 16);
    den += __shfl_xor(den, 32);
#pragma unroll
    for (int j = 0; j < 8; ++j) {
        num[j] += __shfl_xor(num[j], 16);
        num[j] += __shfl_xor(num[j], 32);
    }
    if (slot == 0) {
        float rh = 1.f / den;
        int c0 = li * 8;
        unsigned int o[4];
#pragma unroll
        for (int p = 0; p < 4; ++p) {
            float v0 = fmaf(num[2 * p], rh, bias[c0 + 2 * p]);
            float v1 = fmaf(num[2 * p + 1], rh, bias[c0 + 2 * p + 1]);
            v0 = v0 > 0.f ? v0 : __expf(v0) - 1.f;  // ELU
            v1 = v1 > 0.f ? v1 : __expf(v1) - 1.f;
            o[p] = ((unsigned int)(unsigned short)f2bs(v0)) |
                   (((unsigned int)(unsigned short)f2bs(v1)) << 16);
        }
        out[n * 16 + li] = make_uint4(o[0], o[1], o[2], o[3]);
    }
}

// ------- GraphNorm stats (+ max/min for layer 2) — ATOMIC-FREE ----------------
template <int POOL>
__global__ void __launch_bounds__(256) stats_kernel(
    const uint4* __restrict__ X4, const int* __restrict__ batch,
    float* __restrict__ part, int N) {
    __shared__ float red[16][16][9];  // [rowgroup][u4][ch(+pad)]
    int t = threadIdx.x, u4 = t & 15, rg = t >> 4;
    int base = blockIdx.x * 64;
    int g0 = batch[base];

    float s[2][8] = {}, q[2][8] = {};
    float mx[2][8], mn[2][8];
#pragma unroll
    for (int st = 0; st < 2; ++st)
#pragma unroll
        for (int p = 0; p < 8; ++p) { mx[st][p] = -3e38f; mn[st][p] = 3e38f; }

#pragma unroll
    for (int rr = 0; rr < 4; ++rr) {
        int node = base + rg + rr * 16;
        if (node < N) {
            uint4 hb = X4[node * 16 + u4];
            int st = (batch[node] != g0) ? 1 : 0;
            float vv[8] = {blo(hb.x), bhi(hb.x), blo(hb.y), bhi(hb.y),
                           blo(hb.z), bhi(hb.z), blo(hb.w), bhi(hb.w)};
#pragma unroll
            for (int p = 0; p < 8; ++p) {
                s[st][p] += vv[p];
                q[st][p] += vv[p] * vv[p];
                if (POOL) {
                    mx[st][p] = fmaxf(mx[st][p], vv[p]);
                    mn[st][p] = fminf(mn[st][p], vv[p]);
                }
            }
        }
    }

    int uu = t >> 3, ch = t & 7;  // reducer mapping (threads 0..127 -> channel t)
    float rs[2] = {0.f, 0.f}, rq[2] = {0.f, 0.f};
    float rmx[2] = {-3e38f, -3e38f}, rmn[2] = {3e38f, 3e38f};
    for (int st = 0; st < 2; ++st) {
#pragma unroll
        for (int p = 0; p < 8; ++p) red[rg][u4][p] = s[st][p];
        __syncthreads();
        if (t < 128) { float a = 0.f; for (int r2 = 0; r2 < 16; ++r2) a += red[r2][uu][ch]; rs[st] = a; }
        __syncthreads();
#pragma unroll
        for (int p = 0; p < 8; ++p) red[rg][u4][p] = q[st][p];
        __syncthreads();
        if (t < 128) { float a = 0.f; for (int r2 = 0; r2 < 16; ++r2) a += red[r2][uu][ch]; rq[st] = a; }
        __syncthreads();
        if (POOL) {
#pragma unroll
            for (int p = 0; p < 8; ++p) red[rg][u4][p] = mx[st][p];
            __syncthreads();
            if (t < 128) { float a = -3e38f; for (int r2 = 0; r2 < 16; ++r2) a = fmaxf(a, red[r2][uu][ch]); rmx[st] = a; }
            __syncthreads();
#pragma unroll
            for (int p = 0; p < 8; ++p) red[rg][u4][p] = mn[st][p];
            __syncthreads();
            if (t < 128) { float a = 3e38f; for (int r2 = 0; r2 < 16; ++r2) a = fminf(a, red[r2][uu][ch]); rmn[st] = a; }
            __syncthreads();
        }
    }
    if (t < 128) {
        float* pb = part + (size_t)blockIdx.x * 8 * 128;
        pb[0 * 128 + t] = rs[0];
        pb[1 * 128 + t] = rq[0];
        pb[2 * 128 + t] = rs[1];
        pb[3 * 128 + t] = rq[1];
        if (POOL) {
            pb[4 * 128 + t] = rmx[0];
            pb[5 * 128 + t] = rmn[0];
            pb[6 * 128 + t] = rmx[1];
            pb[7 * 128 + t] = rmn[1];
        }
    }
}

// per-group gather of block partials -> GraphNorm coefficients Ac/Bc.
__global__ void reduce_coef0(const float* __restrict__ part,
                             const int* __restrict__ batch, int N,
                             const float* __restrict__ w, const float* __restrict__ b,
                             const float* __restrict__ ms,
                             float* __restrict__ Ac, float* __restrict__ Bc) {
    __shared__ int sh2[2];
    int g = blockIdx.x, c = threadIdx.x;  // 64 x 128
    if (c < 2) {
        int key = g + c;  // lower_bound(batch, key)
        int lo = 0, hi = N;
        while (lo < hi) { int m = (lo + hi) >> 1; if (batch[m] < key) lo = m + 1; else hi = m; }
        sh2[c] = lo;
    }
    __syncthreads();
    int sidx = sh2[0], eidx = sh2[1];
    float cnt = (float)(eidx - sidx);
    if (cnt < 0.5f) {
        Ac[g * 128 + c] = 0.f;
        Bc[g * 128 + c] = 0.f;
        return;
    }
    int b0 = sidx >> 6, b1 = (eidx - 1) >> 6;
    float s = 0.f, q = 0.f;
    for (int bb = b0; bb <= b1; ++bb) {
        int g0b = batch[bb << 6];
        int qoff;
        bool take;
        if (g0b == g) { qoff = 0; take = true; }
        else {
            int g1b = batch[min((bb << 6) + 63, N - 1)];
            take = (g1b == g);
            qoff = 2;
        }
        if (take) {
            const float* pb = part + (size_t)bb * 8 * 128;
            s += pb[qoff * 128 + c];
            q += pb[(qoff + 1) * 128 + c];
        }
    }
    float mean = s / cnt;
    float msv = ms[c];
    float var = q / cnt - msv * (2.f - msv) * mean * mean;
    var = fmaxf(var, 0.f);
    float inv = rsqrtf(var + EPS_GN);
    float a = w[c] * inv;
    float bb2 = b[c] - msv * mean * a;
    Ac[g * 128 + c] = a;
    Bc[g * 128 + c] = bb2;
}

// per-group partial gather -> GraphNorm coef -> monotone-affine pooled -> FC.
__global__ void rc_fc(const float* __restrict__ part,
                      const int* __restrict__ batch, int N,
                      const float* __restrict__ w, const float* __restrict__ b,
                      const float* __restrict__ ms,
                      const float* __restrict__ fcw,
                      const float* __restrict__ fcb,
                      float* __restrict__ out) {
    __shared__ int sh2[2];
    __shared__ float prow[128];
    int g = blockIdx.x, c = threadIdx.x;  // 64 x 128
    if (c < 2) {
        int key = g + c;  // lower_bound(batch, key)
        int lo = 0, hi = N;
        while (lo < hi) { int m = (lo + hi) >> 1; if (batch[m] < key) lo = m + 1; else hi = m; }
        sh2[c] = lo;
    }
    __syncthreads();
    int sidx = sh2[0], eidx = sh2[1];
    float cnt = (float)(eidx - sidx);
    float pooledv = 0.f;
    if (cnt >= 0.5f) {
        int b0 = sidx >> 6, b1 = (eidx - 1) >> 6;
        float s = 0.f, q = 0.f, M = -3e38f, m = 3e38f;
        for (int bb = b0; bb <= b1; ++bb) {
            int g0b = batch[bb << 6];
            int qoff;
            bool take;
            if (g0b == g) { qoff = 0; take = true; }
            else {
                int g1b = batch[min((bb << 6) + 63, N - 1)];
                take = (g1b == g);
                qoff = 2;
            }
            if (take) {
                const float* pb = part + (size_t)bb * 8 * 128;
                s += pb[qoff * 128 + c];
                q += pb[(qoff + 1) * 128 + c];
                M = fmaxf(M, pb[(4 + qoff) * 128 + c]);
                m = fminf(m, pb[(5 + qoff) * 128 + c]);
            }
        }
        float mean = s / cnt;
        float msv = ms[c];
        float var = q / cnt - msv * (2.f - msv) * mean * mean;
        var = fmaxf(var, 0.f);
        float inv = rsqrtf(var + EPS_GN);
        float a = w[c] * inv;
        float bb2 = b[c] - msv * mean * a;
        pooledv = (a >= 0.f) ? fmaf(a, M, bb2) : fmaf(a, m, bb2);
    }
    prow[c] = pooledv;
    __syncthreads();
    if (c < 64) {
        float acc = fcb[c];
        for (int k = 0; k < 128; ++k)
            acc = fmaf(prow[k], fcw[c * 128 + k], acc);
        out[g * 64 + c] = acc;
    }
}

extern "C" void kernel_launch(void* const* d_in, const int* in_sizes, int n_in,
                              void* d_out, int out_size, void* d_ws, size_t ws_size,
                              hipStream_t stream) {
    const float* x     = (const float*)d_in[0];
    const int* ei      = (const int*)d_in[1];
    const int* batch   = (const int*)d_in[2];
    const float* enc_w = (const float*)d_in[3];
    const float* enc_b = (const float*)d_in[4];
    const float* w1    = (const float*)d_in[5];
    const float* as1   = (const float*)d_in[6];
    const float* ad1   = (const float*)d_in[7];
    const float* b1    = (const float*)d_in[8];
    const float* n1w   = (const float*)d_in[9];
    const float* n1b   = (const float*)d_in[10];
    const float* n1ms  = (const float*)d_in[11];
    const float* w2    = (const float*)d_in[12];
    const float* as2   = (const float*)d_in[13];
    const float* ad2   = (const float*)d_in[14];
    const float* b2    = (const float*)d_in[15];
    const float* n2w   = (const float*)d_in[16];
    const float* n2b   = (const float*)d_in[17];
    const float* n2ms  = (const float*)d_in[18];
    const float* fcw   = (const float*)d_in[19];
    const float* fcb   = (const float*)d_in[20];
    float* out = (float*)d_out;

    int N = in_sizes[2];
    int E = in_sizes[1] / 2;
    int Etot = E + N;
    int SB = (N + 63) / 64;

    char* ws = (char*)d_ws;
    size_t off = 0;
    auto take = [&](size_t bytes) {
        char* p = ws + off;
        off = (off + bytes + 255) & ~(size_t)255;
        return p;
    };
    unsigned short* WT1b = (unsigned short*)take(128 * 128 * 2);
    unsigned short* WT2b = (unsigned short*)take(128 * 128 * 2);
    float* bc1 = (float*)take(512);
    float* bc2 = (float*)take(512);
    float* ssrc = (float*)take((size_t)N * 16);
    float* sdst = (float*)take((size_t)N * 16);
    int* rowp   = (int*)take((size_t)(N + 1) * 4);
    int* esrc   = (int*)take((size_t)Etot * 4);
    unsigned int* staging = (unsigned int*)take((size_t)NBUCK * BCAP * 4);
    int* bcur   = (int*)take(512 * 4);
    unsigned int* H = (unsigned int*)take((size_t)N * 256);  // bf16 [N][128]
    unsigned int* AG = (unsigned int*)take((size_t)N * 256); // bf16 [N][128]
    float* Ac   = (float*)take(64 * 128 * 4);
    float* Bc   = (float*)take(64 * 128 * 4);
    float* part = (float*)take((size_t)SB * 8 * 128 * 4);    // per-block partials
    if (off > ws_size) return;  // workspace too small -> output stays zero

    int EB = (Etot + 4095) / 4096;

    hipMemsetAsync(bcur, 0, 512 * 4, stream);

    // ---- CSR build, hist-free (weight prep fused into scatter; scan folded
    //      into finalize) ----
    bucket_scatter<<<EB, 256, 0, stream>>>(ei, bcur, staging, enc_w, enc_b,
                                           w1, w2, WT1b, WT2b, bc1, bc2, E, N);
    bucket_finalize<<<NBUCK, 256, 0, stream>>>(staging, bcur, rowp, esrc, N, Etot);

    // ---- layer 1 (encoder folded into WT1b/bc1) ----
    gemm_mfma<<<SB, 256, 0, stream>>>(x, WT1b, bc1, as1, ad1, batch,
                                      nullptr, nullptr, H, ssrc, sdst, N);
    agg_kernel<<<(N + 3) / 4, 256, 0, stream>>>(rowp, esrc, ssrc, sdst,
                                                (const uint4*)H, b1, (uint4*)AG, N);
    stats_kernel<0><<<SB, 256, 0, stream>>>((const uint4*)AG, batch, part, N);
    reduce_coef0<<<64, 128, 0, stream>>>(part, batch, N, n1w, n1b, n1ms, Ac, Bc);

    // ---- layer 2 (GraphNorm fused into gemm A-staging; stats+pool one pass) ----
    gemm_mfma<<<SB, 256, 0, stream>>>(AG, WT2b, bc2, as2, ad2, batch,
                                      Ac, Bc, H, ssrc, sdst, N);
    agg_kernel<<<(N + 3) / 4, 256, 0, stream>>>(rowp, esrc, ssrc, sdst,
                                                (const uint4*)H, b2, (uint4*)AG, N);
    stats_kernel<1><<<SB, 256, 0, stream>>>((const uint4*)AG, batch, part, N);
    rc_fc<<<64, 128, 0, stream>>>(part, batch, N, n2w, n2b, n2ms, fcw, fcb, out);
}